// Round 4
// baseline (580.701 us; speedup 1.0000x reference)
//
#include <hip/hip_runtime.h>

typedef float f32x4 __attribute__((ext_vector_type(4)));

// tanh(x) = 1 - 2/(exp(2x)+1), via hardware exp2 + rcp (quarter-rate, ~1 ulp).
// |x| here is bounded (~<10): feat ~ N(0,1), W,b ~ U(-0.707, 0.707), so no
// overflow concerns; saturation to +/-1 is handled naturally.
__device__ __forceinline__ float fast_tanh(float x) {
    float e = __builtin_amdgcn_exp2f(x * 2.885390081777927f); // 2*log2(e)
    float r = __builtin_amdgcn_rcpf(e + 1.0f);
    return fmaf(-2.0f, r, 1.0f);
}

// One row = 32 lanes, each lane produces float4 (16B coalesced store).
// Work item i: row = i>>5, d4 = (i&31)*4.
__global__ __launch_bounds__(256) void bus_embed_kernel(
    const float* __restrict__ feat,      // (N,2)
    const int*   __restrict__ bus_type,  // (N,)
    const float* __restrict__ Ws, const float* __restrict__ bs,
    const float* __restrict__ Wg, const float* __restrict__ bg,
    const float* __restrict__ Wl, const float* __restrict__ bl,
    float* __restrict__ out,             // (N,128)
    int n_rows)
{
    const int total  = n_rows * 32;                // 32M work items
    const int stride = gridDim.x * blockDim.x;
    for (int idx = blockIdx.x * blockDim.x + threadIdx.x; idx < total; idx += stride) {
        const int row = idx >> 5;
        const int d4  = (idx & 31) << 2;

        const float2 f  = *reinterpret_cast<const float2*>(feat + (size_t)row * 2);
        const int    bt = bus_type[row];

        // Branchless 3-way pointer select; bt outside {1,2,3} -> zero via mask.
        const float* W = (bt == 2) ? Wg : (bt == 3) ? Wl : Ws;
        const float* B = (bt == 2) ? bg : (bt == 3) ? bl : bs;
        const float mask = (bt >= 1 && bt <= 3) ? 1.0f : 0.0f;

        const float4 w0 = *reinterpret_cast<const float4*>(W + d4);        // row 0 of W
        const float4 w1 = *reinterpret_cast<const float4*>(W + 128 + d4);  // row 1 of W
        const float4 bb = *reinterpret_cast<const float4*>(B + d4);

        f32x4 o;
        o.x = mask * fast_tanh(fmaf(f.x, w0.x, fmaf(f.y, w1.x, bb.x)));
        o.y = mask * fast_tanh(fmaf(f.x, w0.y, fmaf(f.y, w1.y, bb.y)));
        o.z = mask * fast_tanh(fmaf(f.x, w0.z, fmaf(f.y, w1.z, bb.z)));
        o.w = mask * fast_tanh(fmaf(f.x, w0.w, fmaf(f.y, w1.w, bb.w)));

        // Streaming 512MB output, never re-read: non-temporal store.
        __builtin_nontemporal_store(o, reinterpret_cast<f32x4*>(out + (size_t)row * 128 + d4));
    }
}

extern "C" void kernel_launch(void* const* d_in, const int* in_sizes, int n_in,
                              void* d_out, int out_size, void* d_ws, size_t ws_size,
                              hipStream_t stream) {
    const float* feat = (const float*)d_in[0];
    const int*   bt   = (const int*)d_in[1];
    const float* Ws   = (const float*)d_in[2];
    const float* bs   = (const float*)d_in[3];
    const float* Wg   = (const float*)d_in[4];
    const float* bg   = (const float*)d_in[5];
    const float* Wl   = (const float*)d_in[6];
    const float* bl   = (const float*)d_in[7];
    float* out = (float*)d_out;

    const int n_rows = in_sizes[1];   // bus_type has N elements

    const int block = 256;
    const int grid  = 2048;           // grid-stride; ~61 iters/thread
    bus_embed_kernel<<<grid, block, 0, stream>>>(feat, bt, Ws, bs, Wg, bg, Wl, bl, out, n_rows);
}